// Round 22
// baseline (282.622 us; speedup 1.0000x reference)
//
#include <hip/hip_runtime.h>
#include <hip/hip_bf16.h>

typedef unsigned short ushort_t;
typedef unsigned int uint_t;
typedef __attribute__((ext_vector_type(8))) short bf16x8;
typedef __attribute__((ext_vector_type(4))) float f32x4;

#define NNODE 2000
#define NB 8
#define LSEQ 12
#define HDIM 64
#define NEDGE 16000
#define NSEQ (NNODE * NB)            // 16000 sequences
#define OUT1_ELEMS (NNODE * NB * LSEQ * HDIM)   // 12,288,000
#define OUT1_BYTES (OUT1_ELEMS * 2)             // bf16: 24,576,000
#define AGG_BYTES  (OUT1_ELEMS * 2)             // bf16: 24,576,000
// LDS row stride: multiple of 8 elems (16 B) for ds_read_b128 (R17 lesson).
#define SST 72

__device__ __forceinline__ float bf1(ushort_t u) { return __uint_as_float(((uint_t)u) << 16); }
__device__ __forceinline__ ushort_t fbf(float f) {
    uint_t x = __float_as_uint(f);
    uint_t r = x + 0x7fffu + ((x >> 16) & 1u);   // RNE
    return (ushort_t)(r >> 16);
}
__device__ __forceinline__ float sigm(float x) { return 1.f / (1.f + __expf(-x)); }
__device__ __forceinline__ float tanh_fast(float x) { return 2.f / (1.f + __expf(-2.f * x)) - 1.f; }

// ===========================================================================
// MFMA geometry (HW-verified R3): A[m=lane&15][k=quad*8+jj];
// B[k=ks*32+quad*8+jj][n=lane&15]; C row(M)=quad*4+reg, col(N)=lane&15.
// ===========================================================================

// ---------------------------------------------------------------------------
// MEGA kernel: blocks 0..999 = GRU1 (16 seqs, H ping-pong, 1 barrier/step,
// coalesced out1 writes via Hr copy); block 1000 = CSR build (4-way unrolled
// prefetched loops, R20-proven); blocks 1001..5500 = alpha MLP.
// ---------------------------------------------------------------------------
__global__ __launch_bounds__(256) void mega_kernel(
    const float* __restrict__ data, const float* __restrict__ Wih,
    const float* __restrict__ Whh, const float* __restrict__ bih,
    const float* __restrict__ bhh, ushort_t* __restrict__ out1,
    float* __restrict__ h1out,
    const int* __restrict__ edges, int* __restrict__ degree,
    int* __restrict__ rowstart, int* __restrict__ srcids,
    int* __restrict__ eids,
    const float* __restrict__ features,
    const float* __restrict__ W1, const float* __restrict__ b1,
    const float* __restrict__ W2, const float* __restrict__ b2,
    float* __restrict__ alphas)
{
    __shared__ ushort_t H[2][16][SST] __attribute__((aligned(16)));
    __shared__ float XD[16][26];
    __shared__ int hist[NNODE];
    __shared__ int wsum[4];
    __shared__ float m1[4][16];

    const int bx = blockIdx.x;
    const int tid = threadIdx.x;

    if (bx == 1000) {
        // ================= CSR build (single block, unrolled x4) =========
        for (int k = tid; k < NNODE; k += 256) hist[k] = 0;
        __syncthreads();
        for (int it = 0; it < 16; ++it) {
            const int e0 = it * 1024 + tid;
            int v[4];
#pragma unroll
            for (int k = 0; k < 4; ++k) {
                const int e = e0 + k * 256;
                v[k] = (e < NEDGE) ? edges[NEDGE + e] : -1;
            }
#pragma unroll
            for (int k = 0; k < 4; ++k)
                if (v[k] >= 0) atomicAdd(&hist[v[k]], 1);
        }
        __syncthreads();
        const int lane = tid & 63, w = tid >> 6;
        int d[8];
        int s = 0;
#pragma unroll
        for (int q = 0; q < 8; ++q) {
            const int idx = tid * 8 + q;
            d[q] = (idx < NNODE) ? hist[idx] : 0;
            s += d[q];
        }
        int v = s;
#pragma unroll
        for (int off = 1; off < 64; off <<= 1) {
            int u = __shfl_up(v, off);
            if (lane >= off) v += u;
        }
        if (lane == 63) wsum[w] = v;
        __syncthreads();
        int base = 0;
        for (int k = 0; k < 4; ++k) if (k < w) base += wsum[k];
        int run = base + v - s;
        int rs8[8];
#pragma unroll
        for (int q = 0; q < 8; ++q) {
            const int idx = tid * 8 + q;
            if (idx < NNODE) {
                rs8[q] = run;
                rowstart[idx] = run;
                degree[idx] = d[q];
                run += d[q];
            }
        }
        __syncthreads();
#pragma unroll
        for (int q = 0; q < 8; ++q) {
            const int idx = tid * 8 + q;
            if (idx < NNODE) hist[idx] = rs8[q];
        }
        __syncthreads();
        for (int it = 0; it < 16; ++it) {
            const int e0 = it * 1024 + tid;
            int dv[4], sv[4];
#pragma unroll
            for (int k = 0; k < 4; ++k) {
                const int e = e0 + k * 256;
                dv[k] = (e < NEDGE) ? edges[NEDGE + e] : -1;
                sv[k] = (e < NEDGE) ? edges[e] : 0;
            }
#pragma unroll
            for (int k = 0; k < 4; ++k)
                if (dv[k] >= 0) {
                    const int pos = atomicAdd(&hist[dv[k]], 1);
                    srcids[pos] = sv[k];
                    eids[pos] = e0 + k * 256;
                }
        }
        return;
    }

    if (bx > 1000) {
        // ================= alpha MLP (4 edges/block) =================
        const int w = tid >> 6, lane = tid & 63;
        const int e = (bx - 1001) * 4 + w;
        int i, j;
        if (e < NEDGE) { j = edges[e]; i = edges[NEDGE + e]; }
        else { i = j = e - NEDGE; }
        const int o = lane >> 2, q = lane & 3;
        const float* fsrc = (q < 2) ? (features + i * 64 + q * 32)
                                    : (features + j * 64 + (q - 2) * 32);
        const float* wsrc = W1 + o * 128 + q * 32;
        float acc = 0.f;
#pragma unroll
        for (int k = 0; k < 32; ++k) acc += fsrc[k] * wsrc[k];
        acc += __shfl_xor(acc, 1);
        acc += __shfl_xor(acc, 2);
        if (q == 0) m1[w][o] = sigm(acc + b1[o]);
        __syncthreads();
        if (lane < 32 && e < NEDGE + NNODE) {
            const int o2 = lane >> 4, k = lane & 15;
            float p = m1[w][k] * W2[o2 * 16 + k];
            p += __shfl_xor(p, 1);
            p += __shfl_xor(p, 2);
            p += __shfl_xor(p, 4);
            p += __shfl_xor(p, 8);
            if (k == 0) alphas[e * 2 + o2] = sigm(p + b2[o2]);
        }
        return;
    }

    // ================= GRU1 (blocks 0..999) =================
    const int nw = tid >> 6;
    const int c = tid & 15;
    const int quad = (tid >> 4) & 3;
    const int j = nw * 16 + c;
    const int s0 = bx * 16;
    const int crow = tid >> 4, ccol = (tid & 15) * 4;   // out1 copy mapping (uint2)

    if (tid < 128) *(uint4*)&H[0][tid >> 3][(tid & 7) * 8] = uint4{0, 0, 0, 0};
#pragma unroll
    for (int p = 0; p < 2; ++p) {
        const int flat = p * 256 + tid;
        if (flat < 384) {
            const int sl = flat / 24, q = flat - sl * 24;
            XD[sl][q] = data[(s0 + sl) * 24 + q];
        }
    }

    bf16x8 Bh[3][2];
    float wi0[3], wi1[3], bi[3], bh[3];
#pragma unroll
    for (int g = 0; g < 3; ++g) {
        const int row = g * 64 + j;
        float2 wi = *(const float2*)(Wih + row * 2);
        wi0[g] = wi.x; wi1[g] = wi.y;
        bi[g] = bih[row]; bh[g] = bhh[row];
#pragma unroll
        for (int ks = 0; ks < 2; ++ks) {
            const float* wp = Whh + (row << 6) + ks * 32 + quad * 8;
            float4 wa = *(const float4*)wp;
            float4 wb = *(const float4*)(wp + 4);
            ushort_t tmp[8];
            tmp[0] = fbf(wa.x); tmp[1] = fbf(wa.y); tmp[2] = fbf(wa.z); tmp[3] = fbf(wa.w);
            tmp[4] = fbf(wb.x); tmp[5] = fbf(wb.y); tmp[6] = fbf(wb.z); tmp[7] = fbf(wb.w);
            Bh[g][ks] = *(bf16x8*)tmp;
        }
    }

    float hold[4];
#pragma unroll
    for (int rg = 0; rg < 4; ++rg) hold[rg] = 0.f;

    for (int t = 0; t < LSEQ; ++t) {
        __syncthreads();
        const ushort_t (*Hr)[SST] = H[t & 1];
        ushort_t (*Hw)[SST] = H[1 - (t & 1)];
        bf16x8 a0 = *(const bf16x8*)&Hr[c][quad * 8];
        bf16x8 a1 = *(const bf16x8*)&Hr[c][32 + quad * 8];
        // coalesced out1 write of h_{t-1} from the stable read buffer
        if (t > 0)
            *(uint2*)(out1 + (s0 + crow) * (LSEQ * HDIM) + (t - 1) * HDIM + ccol) =
                *(const uint2*)&Hr[crow][ccol];
        f32x4 gh[3];
#pragma unroll
        for (int g = 0; g < 3; ++g) {
            f32x4 acc = {0.f, 0.f, 0.f, 0.f};
            acc = __builtin_amdgcn_mfma_f32_16x16x32_bf16(a0, Bh[g][0], acc, 0, 0, 0);
            acc = __builtin_amdgcn_mfma_f32_16x16x32_bf16(a1, Bh[g][1], acc, 0, 0, 0);
            gh[g] = acc;
        }
#pragma unroll
        for (int rg = 0; rg < 4; ++rg) {
            const int sloc = quad * 4 + rg;
            float2 xp = *(const float2*)&XD[sloc][2 * t];
            float gr = bh[0] + gh[0][rg];
            float gz = bh[1] + gh[1][rg];
            float gn = bh[2] + gh[2][rg];
            float ir = bi[0] + wi0[0] * xp.x + wi1[0] * xp.y;
            float iz = bi[1] + wi0[1] * xp.x + wi1[1] * xp.y;
            float in = bi[2] + wi0[2] * xp.x + wi1[2] * xp.y;
            float r = sigm(ir + gr);
            float z = sigm(iz + gz);
            float n = tanh_fast(in + r * gn);
            float hv = (1.f - z) * n + z * hold[rg];
            hold[rg] = hv;
            Hw[sloc][j] = fbf(hv);
        }
    }
    __syncthreads();   // final H[LSEQ&1] (= h_{11}) complete
    *(uint2*)(out1 + (s0 + crow) * (LSEQ * HDIM) + (LSEQ - 1) * HDIM + ccol) =
        *(const uint2*)&H[LSEQ & 1][crow][ccol];
#pragma unroll
    for (int rg = 0; rg < 4; ++rg) {
        const int sloc = quad * 4 + rg;
        h1out[(s0 + sloc) * HDIM + j] = hold[rg];
    }
}

// ---------------------------------------------------------------------------
// MetaGAT (CSR, MFMA, K-split, PAIR-BATCHED, 3-way node split; fixed-B-frag
// scheme). SST=72. NEW: 4-slot rotation pool REUSES the Si tile as slot 0
// (Si dead after preamble + self-loop) -> LDS 23->18.4 KB -> 3 blocks/CU.
// One extra barrier between self-loop reads and pair-0 writes.
// ---------------------------------------------------------------------------
__global__ __launch_bounds__(256) void gat_csr_kernel(
    const ushort_t* __restrict__ out1,
    const int* __restrict__ degree, const int* __restrict__ rowstart,
    const int* __restrict__ srcids, const int* __restrict__ eids,
    const float* __restrict__ alphas,
    const float* __restrict__ W3, const float* __restrict__ b3,
    ushort_t* __restrict__ agg)
{
    __shared__ ushort_t POOL[4][32][SST] __attribute__((aligned(16)));  // 18432 B

    const int tid = threadIdx.x;
    const int i = blockIdx.x;
    const int mh = blockIdx.y;            // M-third
    const int deg = degree[i];
    const int rs = rowstart[i];

    const int wv = tid >> 6;              // N-strip
    const int r = tid & 15;
    const int quad = (tid >> 4) & 3;
    const int n = wv * 16 + r;

    // ---- precomputed invariant offsets ----
    int glo[2], lso[2];
#pragma unroll
    for (int p = 0; p < 2; ++p) {
        const int u = p * 256 + tid;
        const int rr = u >> 4, c4 = u & 15;
        const int b = rr & 7, l = (rr >> 3) + 4 * mh;
        glo[p] = (b * 12 + l) * 64 + c4 * 4;
        lso[p] = rr * SST + c4 * 4;
    }
    int afo[2][2];
#pragma unroll
    for (int mt = 0; mt < 2; ++mt) {
        afo[mt][0] = (mt * 16 + r) * SST + quad * 8;
        afo[mt][1] = afo[mt][0] + 32;
    }
    int mgo[8];
#pragma unroll
    for (int mt = 0; mt < 2; ++mt)
#pragma unroll
        for (int g2 = 0; g2 < 4; ++g2)
            mgo[mt * 4 + g2] = (mt * 16 + quad * 4 + g2) * SST + n;

    const ushort_t* pi = out1 + i * (NB * LSEQ * HDIM);
    ushort_t* const sbase = &POOL[0][0][0];
    ushort_t* const Si = sbase;           // slot 0 doubles as Si

    // ---- stage Si (slot 0) ----
#pragma unroll
    for (int p = 0; p < 2; ++p)
        *(uint2*)(Si + lso[p]) = *(const uint2*)(pi + glo[p]);

    // ---- fixed B-frags: top (preamble) and bottom (per-edge) ----
    bf16x8 WtA[2], WtB[2], WtC[2], WbA[2], WbB[2], WbC[2];
#pragma unroll
    for (int ks = 0; ks < 2; ++ks) {
        ushort_t ta[8], tb[8], tc[8], ba[8], bb[8], bc[8];
#pragma unroll
        for (int jj = 0; jj < 8; ++jj) {
            const int mt_ = (ks * 32 + quad * 8 + jj) * 64 + n;
            float2 w2 = ((const float2*)W3)[mt_];
            ta[jj] = fbf(w2.x); tb[jj] = fbf(w2.y); tc[jj] = fbf(b3[mt_]);
            const int mb_ = (64 + ks * 32 + quad * 8 + jj) * 64 + n;
            float2 w2b = ((const float2*)W3)[mb_];
            ba[jj] = fbf(w2b.x); bb[jj] = fbf(w2b.y); bc[jj] = fbf(b3[mb_]);
        }
        WtA[ks] = *(bf16x8*)ta; WtB[ks] = *(bf16x8*)tb; WtC[ks] = *(bf16x8*)tc;
        WbA[ks] = *(bf16x8*)ba; WbB[ks] = *(bf16x8*)bb; WbC[ks] = *(bf16x8*)bc;
    }

    __syncthreads();   // Si ready

    // ---- preamble: Si-projections PA/PB/PC ----
    f32x4 PA[2], PB[2], PC[2];
#pragma unroll
    for (int mt = 0; mt < 2; ++mt) {
        bf16x8 af0 = *(const bf16x8*)(Si + afo[mt][0]);
        bf16x8 af1 = *(const bf16x8*)(Si + afo[mt][1]);
        f32x4 pa = {0.f, 0.f, 0.f, 0.f};
        f32x4 pb = {0.f, 0.f, 0.f, 0.f};
        f32x4 pc = {0.f, 0.f, 0.f, 0.f};
        pa = __builtin_amdgcn_mfma_f32_16x16x32_bf16(af0, WtA[0], pa, 0, 0, 0);
        pa = __builtin_amdgcn_mfma_f32_16x16x32_bf16(af1, WtA[1], pa, 0, 0, 0);
        pb = __builtin_amdgcn_mfma_f32_16x16x32_bf16(af0, WtB[0], pb, 0, 0, 0);
        pb = __builtin_amdgcn_mfma_f32_16x16x32_bf16(af1, WtB[1], pb, 0, 0, 0);
        pc = __builtin_amdgcn_mfma_f32_16x16x32_bf16(af0, WtC[0], pc, 0, 0, 0);
        pc = __builtin_amdgcn_mfma_f32_16x16x32_bf16(af1, WtC[1], pc, 0, 0, 0);
        PA[mt] = pa; PB[mt] = pb; PC[mt] = pc;
    }

    float accN[2][4];
#pragma unroll
    for (int mt = 0; mt < 2; ++mt)
#pragma unroll
        for (int g2 = 0; g2 < 4; ++g2) accN[mt][g2] = 0.f;

    auto process = [&](const ushort_t* SB, float2 a01) {
#pragma unroll
        for (int mt = 0; mt < 2; ++mt) {
            bf16x8 aj0 = *(const bf16x8*)(SB + afo[mt][0]);
            bf16x8 aj1 = *(const bf16x8*)(SB + afo[mt][1]);
            f32x4 aA = PA[mt], aB = PB[mt], aC = PC[mt];
            aA = __builtin_amdgcn_mfma_f32_16x16x32_bf16(aj0, WbA[0], aA, 0, 0, 0);
            aA = __builtin_amdgcn_mfma_f32_16x16x32_bf16(aj1, WbA[1], aA, 0, 0, 0);
            aB = __builtin_amdgcn_mfma_f32_16x16x32_bf16(aj0, WbB[0], aB, 0, 0, 0);
            aB = __builtin_amdgcn_mfma_f32_16x16x32_bf16(aj1, WbB[1], aB, 0, 0, 0);
            aC = __builtin_amdgcn_mfma_f32_16x16x32_bf16(aj0, WbC[0], aC, 0, 0, 0);
            aC = __builtin_amdgcn_mfma_f32_16x16x32_bf16(aj1, WbC[1], aC, 0, 0, 0);
            float v[4];
            float s = 0.f;
#pragma unroll
            for (int g2 = 0; g2 < 4; ++g2) {
                float x = fmaf(a01.x, aA[g2], fmaf(a01.y, aB[g2], aC[g2]));
                x = x > 0.f ? x : 0.01f * x;   // leaky_relu
                v[g2] = __expf(x);             // |x| small: safe w/o max-sub
                s += v[g2];
            }
            s += __shfl_xor(s, 16);
            const float inv = 1.f / s;
#pragma unroll
            for (int g2 = 0; g2 < 4; ++g2)
                accN[mt][g2] += v[g2] * inv * bf1(SB[mgo[mt * 4 + g2]]);
        }
    };

    // ---- prefetch CSR edges 0,1 into registers ----
    uint2 pfA[2], pfB[2];
    {
        const ushort_t* pA = out1 + ((deg >= 1) ? srcids[rs] : 0) * (NB * LSEQ * HDIM);
        const ushort_t* pB = out1 + ((deg >= 2) ? srcids[rs + 1] : 0) * (NB * LSEQ * HDIM);
#pragma unroll
        for (int p = 0; p < 2; ++p) {
            pfA[p] = *(const uint2*)(pA + glo[p]);
            pfB[p] = *(const uint2*)(pB + glo[p]);
        }
    }

    // ---- self loop (reads slot 0 = Si) ----
    process(Si, *(const float2*)(alphas + (NEDGE + i) * 2));
    __syncthreads();   // all waves done reading Si before pair 0 overwrites it

    const int npairs = (deg + 1) >> 1;
    for (int pk = 0; pk < npairs; ++pk) {
        ushort_t* SA = sbase + (2 * (pk & 1)) * (32 * SST);
        ushort_t* SB = SA + 32 * SST;
#pragma unroll
        for (int p = 0; p < 2; ++p) {
            *(uint2*)(SA + lso[p]) = pfA[p];
            *(uint2*)(SB + lso[p]) = pfB[p];
        }
        const int base = pk * 2;
        const float2 aA = *(const float2*)(alphas + eids[rs + base] * 2);
        const bool hasB = (base + 1) < deg;
        float2 aB = float2{0.f, 0.f};
        if (hasB) aB = *(const float2*)(alphas + eids[rs + base + 1] * 2);
        __syncthreads();   // pair tiles ready (pk-1 slots fully read pre-barrier)

        if (base + 2 < deg) {
            const ushort_t* pA = out1 + srcids[rs + base + 2] * (NB * LSEQ * HDIM);
#pragma unroll
            for (int p = 0; p < 2; ++p) pfA[p] = *(const uint2*)(pA + glo[p]);
        }
        if (base + 3 < deg) {
            const ushort_t* pB = out1 + srcids[rs + base + 3] * (NB * LSEQ * HDIM);
#pragma unroll
            for (int p = 0; p < 2; ++p) pfB[p] = *(const uint2*)(pB + glo[p]);
        }

        process(SA, aA);
        if (hasB) process(SB, aB);
    }

    // single non-atomic bf16 store of this third-node's aggregate
#pragma unroll
    for (int mt = 0; mt < 2; ++mt)
#pragma unroll
        for (int g2 = 0; g2 < 4; ++g2) {
            const int gr = mh * 32 + mt * 16 + quad * 4 + g2;  // = l*8 + b
            const int b = gr & 7, l = gr >> 3;
            agg[(i * 96 + b * 12 + l) * 64 + n] = fbf(accN[mt][g2]);
        }
}

// ---------------------------------------------------------------------------
// GRU2 (R18 version, validated): gi AND gh via MFMA; x = relu(agg bf16).
// 16 seqs / 4 waves per block, single barrier per step via H+X ping-pong;
// next x prefetched under MFMAs.
// ---------------------------------------------------------------------------
__global__ __launch_bounds__(256) void gru2_kernel(
    const ushort_t* __restrict__ agg, const float* __restrict__ Wih,
    const float* __restrict__ Whh, const float* __restrict__ bih,
    const float* __restrict__ bhh, float* __restrict__ h2out)
{
    __shared__ ushort_t H[2][16][SST] __attribute__((aligned(16)));
    __shared__ ushort_t X[2][16][SST] __attribute__((aligned(16)));

    const int tid = threadIdx.x;
    const int nw = tid >> 6;
    const int c = tid & 15;
    const int quad = (tid >> 4) & 3;
    const int j = nw * 16 + c;
    const int s0 = blockIdx.x * 16;
    const int sl = tid >> 3, k0 = (tid & 7) * 8;

    if (tid < 128) *(uint4*)&H[0][tid >> 3][(tid & 7) * 8] = uint4{0, 0, 0, 0};

    bf16x8 Bh[3][2], Bi[3][2];
    float bi[3], bh[3];
#pragma unroll
    for (int g = 0; g < 3; ++g) {
        const int row = g * 64 + j;
        bi[g] = bih[row]; bh[g] = bhh[row];
#pragma unroll
        for (int ks = 0; ks < 2; ++ks) {
            const float* wp = Whh + (row << 6) + ks * 32 + quad * 8;
            float4 wa = *(const float4*)wp;
            float4 wb = *(const float4*)(wp + 4);
            ushort_t tmp[8];
            tmp[0] = fbf(wa.x); tmp[1] = fbf(wa.y); tmp[2] = fbf(wa.z); tmp[3] = fbf(wa.w);
            tmp[4] = fbf(wb.x); tmp[5] = fbf(wb.y); tmp[6] = fbf(wb.z); tmp[7] = fbf(wb.w);
            Bh[g][ks] = *(bf16x8*)tmp;
            const float* wp2 = Wih + (row << 6) + ks * 32 + quad * 8;
            float4 va = *(const float4*)wp2;
            float4 vb = *(const float4*)(wp2 + 4);
            tmp[0] = fbf(va.x); tmp[1] = fbf(va.y); tmp[2] = fbf(va.z); tmp[3] = fbf(va.w);
            tmp[4] = fbf(vb.x); tmp[5] = fbf(vb.y); tmp[6] = fbf(vb.z); tmp[7] = fbf(vb.w);
            Bi[g][ks] = *(bf16x8*)tmp;
        }
    }

    float hold[4];
#pragma unroll
    for (int rg = 0; rg < 4; ++rg) hold[rg] = 0.f;

    if (tid < 128) {
        ushort_t xr[8];
        *(uint4*)xr = *(const uint4*)(agg + (s0 + sl) * (LSEQ * HDIM) + k0);
        ushort_t xs[8];
#pragma unroll
        for (int q = 0; q < 8; ++q) xs[q] = (xr[q] & 0x8000u) ? (ushort_t)0 : xr[q];
        *(uint4*)&X[0][sl][k0] = *(uint4*)xs;
    }

    for (int t = 0; t < LSEQ; ++t) {
        __syncthreads();
        const int rb = t & 1, wb = 1 - rb;
        bf16x8 ah0 = *(const bf16x8*)&H[rb][c][quad * 8];
        bf16x8 ah1 = *(const bf16x8*)&H[rb][c][32 + quad * 8];
        bf16x8 ax0 = *(const bf16x8*)&X[rb][c][quad * 8];
        bf16x8 ax1 = *(const bf16x8*)&X[rb][c][32 + quad * 8];

        ushort_t xr[8];
        if (t < LSEQ - 1 && tid < 128)
            *(uint4*)xr = *(const uint4*)(agg + (s0 + sl) * (LSEQ * HDIM) +
                                          (t + 1) * HDIM + k0);

        f32x4 gh[3], gi[3];
#pragma unroll
        for (int g = 0; g < 3; ++g) {
            f32x4 acc = {0.f, 0.f, 0.f, 0.f};
            acc = __builtin_amdgcn_mfma_f32_16x16x32_bf16(ah0, Bh[g][0], acc, 0, 0, 0);
            acc = __builtin_amdgcn_mfma_f32_16x16x32_bf16(ah1, Bh[g][1], acc, 0, 0, 0);
            gh[g] = acc;
            f32x4 acc2 = {0.f, 0.f, 0.f, 0.f};
            acc2 = __builtin_amdgcn_mfma_f32_16x16x32_bf16(ax0, Bi[g][0], acc2, 0, 0, 0);
            acc2 = __builtin_amdgcn_mfma_f32_16x16x32_bf16(ax1, Bi[g][1], acc2, 0, 0, 0);
            gi[g] = acc2;
        }
#pragma unroll
        for (int rg = 0; rg < 4; ++rg) {
            const int sloc = quad * 4 + rg;
            float r = sigm(bi[0] + gi[0][rg] + bh[0] + gh[0][rg]);
            float z = sigm(bi[1] + gi[1][rg] + bh[1] + gh[1][rg]);
            float n = tanh_fast(bi[2] + gi[2][rg] + r * (bh[2] + gh[2][rg]));
            float hv = (1.f - z) * n + z * hold[rg];
            hold[rg] = hv;
            H[wb][sloc][j] = fbf(hv);
        }
        if (t < LSEQ - 1 && tid < 128) {
            ushort_t xs[8];
#pragma unroll
            for (int q = 0; q < 8; ++q) xs[q] = (xr[q] & 0x8000u) ? (ushort_t)0 : xr[q];
            *(uint4*)&X[wb][sl][k0] = *(uint4*)xs;
        }
    }
#pragma unroll
    for (int rg = 0; rg < 4; ++rg) {
        const int sloc = quad * 4 + rg;
        h2out[(s0 + sloc) * HDIM + j] = hold[rg];
    }
}

extern "C" void kernel_launch(void* const* d_in, const int* in_sizes, int n_in,
                              void* d_out, int out_size, void* d_ws, size_t ws_size,
                              hipStream_t stream)
{
    const float* data     = (const float*)d_in[0];
    const float* features = (const float*)d_in[1];
    const int*   edges    = (const int*)d_in[2];
    const float* Wih1     = (const float*)d_in[3];
    const float* Whh1     = (const float*)d_in[4];
    const float* bih1     = (const float*)d_in[5];
    const float* bhh1     = (const float*)d_in[6];
    const float* W1       = (const float*)d_in[7];
    const float* b1       = (const float*)d_in[8];
    const float* W2       = (const float*)d_in[9];
    const float* b2       = (const float*)d_in[10];
    const float* W3       = (const float*)d_in[11];
    const float* b3       = (const float*)d_in[12];
    const float* Wih2     = (const float*)d_in[13];
    const float* Whh2     = (const float*)d_in[14];
    const float* bih2     = (const float*)d_in[15];
    const float* bhh2     = (const float*)d_in[16];

    float*    out  = (float*)d_out;
    char*     ws   = (char*)d_ws;
    ushort_t* out1 = (ushort_t*)ws;                    // bf16 intermediate
    ushort_t* agg  = (ushort_t*)(ws + OUT1_BYTES);     // bf16 GAT output
    int*      meta = (int*)(ws + OUT1_BYTES + AGG_BYTES);
    int*   degree   = meta;                       // [2000]
    int*   rowstart = meta + NNODE;               // [2000]
    int*   srcids   = meta + 2 * NNODE;           // [16000]
    int*   eids     = meta + 2 * NNODE + NEDGE;   // [16000]
    float* alphas   = (float*)(meta + 2 * NNODE + 2 * NEDGE);  // [36000]

    // 3 dispatches: mega (gru1 || csr || alpha), gat, gru2.
    mega_kernel<<<1001 + 4500, 256, 0, stream>>>(
        data, Wih1, Whh1, bih1, bhh1, out1, out,
        edges, degree, rowstart, srcids, eids,
        features, W1, b1, W2, b2, alphas);
    gat_csr_kernel<<<dim3(NNODE, 3), 256, 0, stream>>>(out1, degree, rowstart, srcids,
                                                       eids, alphas, W3, b3, agg);
    gru2_kernel<<<NSEQ / 16, 256, 0, stream>>>(agg, Wih2, Whh2, bih2, bhh2,
                                               out + NNODE * NB * HDIM);
}

// Round 23
// 270.744 us; speedup vs baseline: 1.0439x; 1.0439x over previous
//
#include <hip/hip_runtime.h>
#include <hip/hip_bf16.h>

typedef unsigned short ushort_t;
typedef unsigned int uint_t;
typedef __attribute__((ext_vector_type(8))) short bf16x8;
typedef __attribute__((ext_vector_type(4))) float f32x4;

#define NNODE 2000
#define NB 8
#define LSEQ 12
#define HDIM 64
#define NEDGE 16000
#define NSEQ (NNODE * NB)            // 16000 sequences
#define OUT1_ELEMS (NNODE * NB * LSEQ * HDIM)   // 12,288,000
#define OUT1_BYTES (OUT1_ELEMS * 2)             // bf16: 24,576,000
#define AGG_BYTES  (OUT1_ELEMS * 2)             // bf16: 24,576,000
// LDS row stride: multiple of 8 elems (16 B) for ds_read_b128 (R17 lesson).
#define SST 72

__device__ __forceinline__ float bf1(ushort_t u) { return __uint_as_float(((uint_t)u) << 16); }
__device__ __forceinline__ ushort_t fbf(float f) {
    uint_t x = __float_as_uint(f);
    uint_t r = x + 0x7fffu + ((x >> 16) & 1u);   // RNE
    return (ushort_t)(r >> 16);
}
__device__ __forceinline__ float sigm(float x) { return 1.f / (1.f + __expf(-x)); }
__device__ __forceinline__ float tanh_fast(float x) { return 2.f / (1.f + __expf(-2.f * x)) - 1.f; }

// ===========================================================================
// MFMA geometry (HW-verified R3): A[m=lane&15][k=quad*8+jj];
// B[k=ks*32+quad*8+jj][n=lane&15]; C row(M)=quad*4+reg, col(N)=lane&15.
// ===========================================================================

// ---------------------------------------------------------------------------
// MEGA kernel: blocks 0..999 = GRU1 (16 seqs, H ping-pong, 1 barrier/step,
// coalesced out1 writes); block 1000 = CSR build (4-way unrolled) + degree-
// DESCENDING counting sort -> order[] (longest gat blocks scheduled first);
// blocks 1001..5500 = alpha MLP.
// ---------------------------------------------------------------------------
__global__ __launch_bounds__(256) void mega_kernel(
    const float* __restrict__ data, const float* __restrict__ Wih,
    const float* __restrict__ Whh, const float* __restrict__ bih,
    const float* __restrict__ bhh, ushort_t* __restrict__ out1,
    float* __restrict__ h1out,
    const int* __restrict__ edges, int* __restrict__ degree,
    int* __restrict__ rowstart, int* __restrict__ srcids,
    int* __restrict__ eids, int* __restrict__ order,
    const float* __restrict__ features,
    const float* __restrict__ W1, const float* __restrict__ b1,
    const float* __restrict__ W2, const float* __restrict__ b2,
    float* __restrict__ alphas)
{
    __shared__ ushort_t H[2][16][SST] __attribute__((aligned(16)));
    __shared__ float XD[16][26];
    __shared__ int hist[NNODE];
    __shared__ int wsum[4];
    __shared__ float m1[4][16];
    __shared__ int dh[64];

    const int bx = blockIdx.x;
    const int tid = threadIdx.x;

    if (bx == 1000) {
        // ================= CSR build (single block, unrolled x4) =========
        for (int k = tid; k < NNODE; k += 256) hist[k] = 0;
        if (tid < 64) dh[tid] = 0;
        __syncthreads();
        for (int it = 0; it < 16; ++it) {
            const int e0 = it * 1024 + tid;
            int v[4];
#pragma unroll
            for (int k = 0; k < 4; ++k) {
                const int e = e0 + k * 256;
                v[k] = (e < NEDGE) ? edges[NEDGE + e] : -1;
            }
#pragma unroll
            for (int k = 0; k < 4; ++k)
                if (v[k] >= 0) atomicAdd(&hist[v[k]], 1);
        }
        __syncthreads();
        const int lane = tid & 63, w = tid >> 6;
        int d[8];
        int s = 0;
#pragma unroll
        for (int q = 0; q < 8; ++q) {
            const int idx = tid * 8 + q;
            d[q] = (idx < NNODE) ? hist[idx] : 0;
            s += d[q];
        }
        int v = s;
#pragma unroll
        for (int off = 1; off < 64; off <<= 1) {
            int u = __shfl_up(v, off);
            if (lane >= off) v += u;
        }
        if (lane == 63) wsum[w] = v;
        __syncthreads();
        int base = 0;
        for (int k = 0; k < 4; ++k) if (k < w) base += wsum[k];
        int run = base + v - s;
        int rs8[8];
#pragma unroll
        for (int q = 0; q < 8; ++q) {
            const int idx = tid * 8 + q;
            if (idx < NNODE) {
                rs8[q] = run;
                rowstart[idx] = run;
                degree[idx] = d[q];
                run += d[q];
                atomicAdd(&dh[63 - min(d[q], 63)], 1);   // descending-degree key
            }
        }
        __syncthreads();
        if (tid == 0) {          // serial prefix over 64 buckets
            int acc = 0;
            for (int k = 0; k < 64; ++k) { const int c = dh[k]; dh[k] = acc; acc += c; }
        }
        __syncthreads();
        // scatter nodes into order[] (longest first)
#pragma unroll
        for (int q = 0; q < 8; ++q) {
            const int idx = tid * 8 + q;
            if (idx < NNODE) {
                const int pos = atomicAdd(&dh[63 - min(d[q], 63)], 1);
                order[pos] = idx;
            }
        }
        // reuse hist as scatter cursor
        __syncthreads();
#pragma unroll
        for (int q = 0; q < 8; ++q) {
            const int idx = tid * 8 + q;
            if (idx < NNODE) hist[idx] = rs8[q];
        }
        __syncthreads();
        for (int it = 0; it < 16; ++it) {
            const int e0 = it * 1024 + tid;
            int dv[4], sv[4];
#pragma unroll
            for (int k = 0; k < 4; ++k) {
                const int e = e0 + k * 256;
                dv[k] = (e < NEDGE) ? edges[NEDGE + e] : -1;
                sv[k] = (e < NEDGE) ? edges[e] : 0;
            }
#pragma unroll
            for (int k = 0; k < 4; ++k)
                if (dv[k] >= 0) {
                    const int pos = atomicAdd(&hist[dv[k]], 1);
                    srcids[pos] = sv[k];
                    eids[pos] = e0 + k * 256;
                }
        }
        return;
    }

    if (bx > 1000) {
        // ================= alpha MLP (4 edges/block) =================
        const int w = tid >> 6, lane = tid & 63;
        const int e = (bx - 1001) * 4 + w;
        int i, j;
        if (e < NEDGE) { j = edges[e]; i = edges[NEDGE + e]; }
        else { i = j = e - NEDGE; }
        const int o = lane >> 2, q = lane & 3;
        const float* fsrc = (q < 2) ? (features + i * 64 + q * 32)
                                    : (features + j * 64 + (q - 2) * 32);
        const float* wsrc = W1 + o * 128 + q * 32;
        float acc = 0.f;
#pragma unroll
        for (int k = 0; k < 32; ++k) acc += fsrc[k] * wsrc[k];
        acc += __shfl_xor(acc, 1);
        acc += __shfl_xor(acc, 2);
        if (q == 0) m1[w][o] = sigm(acc + b1[o]);
        __syncthreads();
        if (lane < 32 && e < NEDGE + NNODE) {
            const int o2 = lane >> 4, k = lane & 15;
            float p = m1[w][k] * W2[o2 * 16 + k];
            p += __shfl_xor(p, 1);
            p += __shfl_xor(p, 2);
            p += __shfl_xor(p, 4);
            p += __shfl_xor(p, 8);
            if (k == 0) alphas[e * 2 + o2] = sigm(p + b2[o2]);
        }
        return;
    }

    // ================= GRU1 (blocks 0..999) =================
    const int nw = tid >> 6;
    const int c = tid & 15;
    const int quad = (tid >> 4) & 3;
    const int j = nw * 16 + c;
    const int s0 = bx * 16;
    const int crow = tid >> 4, ccol = (tid & 15) * 4;   // out1 copy mapping (uint2)

    if (tid < 128) *(uint4*)&H[0][tid >> 3][(tid & 7) * 8] = uint4{0, 0, 0, 0};
#pragma unroll
    for (int p = 0; p < 2; ++p) {
        const int flat = p * 256 + tid;
        if (flat < 384) {
            const int sl = flat / 24, q = flat - sl * 24;
            XD[sl][q] = data[(s0 + sl) * 24 + q];
        }
    }

    bf16x8 Bh[3][2];
    float wi0[3], wi1[3], bi[3], bh[3];
#pragma unroll
    for (int g = 0; g < 3; ++g) {
        const int row = g * 64 + j;
        float2 wi = *(const float2*)(Wih + row * 2);
        wi0[g] = wi.x; wi1[g] = wi.y;
        bi[g] = bih[row]; bh[g] = bhh[row];
#pragma unroll
        for (int ks = 0; ks < 2; ++ks) {
            const float* wp = Whh + (row << 6) + ks * 32 + quad * 8;
            float4 wa = *(const float4*)wp;
            float4 wb = *(const float4*)(wp + 4);
            ushort_t tmp[8];
            tmp[0] = fbf(wa.x); tmp[1] = fbf(wa.y); tmp[2] = fbf(wa.z); tmp[3] = fbf(wa.w);
            tmp[4] = fbf(wb.x); tmp[5] = fbf(wb.y); tmp[6] = fbf(wb.z); tmp[7] = fbf(wb.w);
            Bh[g][ks] = *(bf16x8*)tmp;
        }
    }

    float hold[4];
#pragma unroll
    for (int rg = 0; rg < 4; ++rg) hold[rg] = 0.f;

    for (int t = 0; t < LSEQ; ++t) {
        __syncthreads();
        const ushort_t (*Hr)[SST] = H[t & 1];
        ushort_t (*Hw)[SST] = H[1 - (t & 1)];
        bf16x8 a0 = *(const bf16x8*)&Hr[c][quad * 8];
        bf16x8 a1 = *(const bf16x8*)&Hr[c][32 + quad * 8];
        // coalesced out1 write of h_{t-1} from the stable read buffer
        if (t > 0)
            *(uint2*)(out1 + (s0 + crow) * (LSEQ * HDIM) + (t - 1) * HDIM + ccol) =
                *(const uint2*)&Hr[crow][ccol];
        f32x4 gh[3];
#pragma unroll
        for (int g = 0; g < 3; ++g) {
            f32x4 acc = {0.f, 0.f, 0.f, 0.f};
            acc = __builtin_amdgcn_mfma_f32_16x16x32_bf16(a0, Bh[g][0], acc, 0, 0, 0);
            acc = __builtin_amdgcn_mfma_f32_16x16x32_bf16(a1, Bh[g][1], acc, 0, 0, 0);
            gh[g] = acc;
        }
#pragma unroll
        for (int rg = 0; rg < 4; ++rg) {
            const int sloc = quad * 4 + rg;
            float2 xp = *(const float2*)&XD[sloc][2 * t];
            float gr = bh[0] + gh[0][rg];
            float gz = bh[1] + gh[1][rg];
            float gn = bh[2] + gh[2][rg];
            float ir = bi[0] + wi0[0] * xp.x + wi1[0] * xp.y;
            float iz = bi[1] + wi0[1] * xp.x + wi1[1] * xp.y;
            float in = bi[2] + wi0[2] * xp.x + wi1[2] * xp.y;
            float r = sigm(ir + gr);
            float z = sigm(iz + gz);
            float n = tanh_fast(in + r * gn);
            float hv = (1.f - z) * n + z * hold[rg];
            hold[rg] = hv;
            Hw[sloc][j] = fbf(hv);
        }
    }
    __syncthreads();   // final H[LSEQ&1] (= h_{11}) complete
    *(uint2*)(out1 + (s0 + crow) * (LSEQ * HDIM) + (LSEQ - 1) * HDIM + ccol) =
        *(const uint2*)&H[LSEQ & 1][crow][ccol];
#pragma unroll
    for (int rg = 0; rg < 4; ++rg) {
        const int sloc = quad * 4 + rg;
        h1out[(s0 + sloc) * HDIM + j] = hold[rg];
    }
}

// ---------------------------------------------------------------------------
// MetaGAT (CSR, MFMA, K-split, PAIR-BATCHED, 3-way node split; fixed-B-frag
// scheme). SST=72, 18.4 KB (Si = slot 0, R22). Node picked via order[] --
// longest blocks dispatch first (tail trim).
// ---------------------------------------------------------------------------
__global__ __launch_bounds__(256) void gat_csr_kernel(
    const ushort_t* __restrict__ out1,
    const int* __restrict__ degree, const int* __restrict__ rowstart,
    const int* __restrict__ srcids, const int* __restrict__ eids,
    const int* __restrict__ order,
    const float* __restrict__ alphas,
    const float* __restrict__ W3, const float* __restrict__ b3,
    ushort_t* __restrict__ agg)
{
    __shared__ ushort_t POOL[4][32][SST] __attribute__((aligned(16)));  // 18432 B

    const int tid = threadIdx.x;
    const int i = order[blockIdx.x];      // degree-descending schedule
    const int mh = blockIdx.y;            // M-third
    const int deg = degree[i];
    const int rs = rowstart[i];

    const int wv = tid >> 6;              // N-strip
    const int r = tid & 15;
    const int quad = (tid >> 4) & 3;
    const int n = wv * 16 + r;

    // ---- precomputed invariant offsets ----
    int glo[2], lso[2];
#pragma unroll
    for (int p = 0; p < 2; ++p) {
        const int u = p * 256 + tid;
        const int rr = u >> 4, c4 = u & 15;
        const int b = rr & 7, l = (rr >> 3) + 4 * mh;
        glo[p] = (b * 12 + l) * 64 + c4 * 4;
        lso[p] = rr * SST + c4 * 4;
    }
    int afo[2][2];
#pragma unroll
    for (int mt = 0; mt < 2; ++mt) {
        afo[mt][0] = (mt * 16 + r) * SST + quad * 8;
        afo[mt][1] = afo[mt][0] + 32;
    }
    int mgo[8];
#pragma unroll
    for (int mt = 0; mt < 2; ++mt)
#pragma unroll
        for (int g2 = 0; g2 < 4; ++g2)
            mgo[mt * 4 + g2] = (mt * 16 + quad * 4 + g2) * SST + n;

    const ushort_t* pi = out1 + i * (NB * LSEQ * HDIM);
    ushort_t* const sbase = &POOL[0][0][0];
    ushort_t* const Si = sbase;           // slot 0 doubles as Si

    // ---- stage Si (slot 0) ----
#pragma unroll
    for (int p = 0; p < 2; ++p)
        *(uint2*)(Si + lso[p]) = *(const uint2*)(pi + glo[p]);

    // ---- fixed B-frags: top (preamble) and bottom (per-edge) ----
    bf16x8 WtA[2], WtB[2], WtC[2], WbA[2], WbB[2], WbC[2];
#pragma unroll
    for (int ks = 0; ks < 2; ++ks) {
        ushort_t ta[8], tb[8], tc[8], ba[8], bb[8], bc[8];
#pragma unroll
        for (int jj = 0; jj < 8; ++jj) {
            const int mt_ = (ks * 32 + quad * 8 + jj) * 64 + n;
            float2 w2 = ((const float2*)W3)[mt_];
            ta[jj] = fbf(w2.x); tb[jj] = fbf(w2.y); tc[jj] = fbf(b3[mt_]);
            const int mb_ = (64 + ks * 32 + quad * 8 + jj) * 64 + n;
            float2 w2b = ((const float2*)W3)[mb_];
            ba[jj] = fbf(w2b.x); bb[jj] = fbf(w2b.y); bc[jj] = fbf(b3[mb_]);
        }
        WtA[ks] = *(bf16x8*)ta; WtB[ks] = *(bf16x8*)tb; WtC[ks] = *(bf16x8*)tc;
        WbA[ks] = *(bf16x8*)ba; WbB[ks] = *(bf16x8*)bb; WbC[ks] = *(bf16x8*)bc;
    }

    __syncthreads();   // Si ready

    // ---- preamble: Si-projections PA/PB/PC ----
    f32x4 PA[2], PB[2], PC[2];
#pragma unroll
    for (int mt = 0; mt < 2; ++mt) {
        bf16x8 af0 = *(const bf16x8*)(Si + afo[mt][0]);
        bf16x8 af1 = *(const bf16x8*)(Si + afo[mt][1]);
        f32x4 pa = {0.f, 0.f, 0.f, 0.f};
        f32x4 pb = {0.f, 0.f, 0.f, 0.f};
        f32x4 pc = {0.f, 0.f, 0.f, 0.f};
        pa = __builtin_amdgcn_mfma_f32_16x16x32_bf16(af0, WtA[0], pa, 0, 0, 0);
        pa = __builtin_amdgcn_mfma_f32_16x16x32_bf16(af1, WtA[1], pa, 0, 0, 0);
        pb = __builtin_amdgcn_mfma_f32_16x16x32_bf16(af0, WtB[0], pb, 0, 0, 0);
        pb = __builtin_amdgcn_mfma_f32_16x16x32_bf16(af1, WtB[1], pb, 0, 0, 0);
        pc = __builtin_amdgcn_mfma_f32_16x16x32_bf16(af0, WtC[0], pc, 0, 0, 0);
        pc = __builtin_amdgcn_mfma_f32_16x16x32_bf16(af1, WtC[1], pc, 0, 0, 0);
        PA[mt] = pa; PB[mt] = pb; PC[mt] = pc;
    }

    float accN[2][4];
#pragma unroll
    for (int mt = 0; mt < 2; ++mt)
#pragma unroll
        for (int g2 = 0; g2 < 4; ++g2) accN[mt][g2] = 0.f;

    auto process = [&](const ushort_t* SB, float2 a01) {
#pragma unroll
        for (int mt = 0; mt < 2; ++mt) {
            bf16x8 aj0 = *(const bf16x8*)(SB + afo[mt][0]);
            bf16x8 aj1 = *(const bf16x8*)(SB + afo[mt][1]);
            f32x4 aA = PA[mt], aB = PB[mt], aC = PC[mt];
            aA = __builtin_amdgcn_mfma_f32_16x16x32_bf16(aj0, WbA[0], aA, 0, 0, 0);
            aA = __builtin_amdgcn_mfma_f32_16x16x32_bf16(aj1, WbA[1], aA, 0, 0, 0);
            aB = __builtin_amdgcn_mfma_f32_16x16x32_bf16(aj0, WbB[0], aB, 0, 0, 0);
            aB = __builtin_amdgcn_mfma_f32_16x16x32_bf16(aj1, WbB[1], aB, 0, 0, 0);
            aC = __builtin_amdgcn_mfma_f32_16x16x32_bf16(aj0, WbC[0], aC, 0, 0, 0);
            aC = __builtin_amdgcn_mfma_f32_16x16x32_bf16(aj1, WbC[1], aC, 0, 0, 0);
            float v[4];
            float s = 0.f;
#pragma unroll
            for (int g2 = 0; g2 < 4; ++g2) {
                float x = fmaf(a01.x, aA[g2], fmaf(a01.y, aB[g2], aC[g2]));
                x = x > 0.f ? x : 0.01f * x;   // leaky_relu
                v[g2] = __expf(x);             // |x| small: safe w/o max-sub
                s += v[g2];
            }
            s += __shfl_xor(s, 16);
            const float inv = 1.f / s;
#pragma unroll
            for (int g2 = 0; g2 < 4; ++g2)
                accN[mt][g2] += v[g2] * inv * bf1(SB[mgo[mt * 4 + g2]]);
        }
    };

    // ---- prefetch CSR edges 0,1 into registers ----
    uint2 pfA[2], pfB[2];
    {
        const ushort_t* pA = out1 + ((deg >= 1) ? srcids[rs] : 0) * (NB * LSEQ * HDIM);
        const ushort_t* pB = out1 + ((deg >= 2) ? srcids[rs + 1] : 0) * (NB * LSEQ * HDIM);
#pragma unroll
        for (int p = 0; p < 2; ++p) {
            pfA[p] = *(const uint2*)(pA + glo[p]);
            pfB[p] = *(const uint2*)(pB + glo[p]);
        }
    }

    // ---- self loop (reads slot 0 = Si) ----
    process(Si, *(const float2*)(alphas + (NEDGE + i) * 2));
    __syncthreads();   // all waves done reading Si before pair 0 overwrites it

    const int npairs = (deg + 1) >> 1;
    for (int pk = 0; pk < npairs; ++pk) {
        ushort_t* SA = sbase + (2 * (pk & 1)) * (32 * SST);
        ushort_t* SB = SA + 32 * SST;
#pragma unroll
        for (int p = 0; p < 2; ++p) {
            *(uint2*)(SA + lso[p]) = pfA[p];
            *(uint2*)(SB + lso[p]) = pfB[p];
        }
        const int base = pk * 2;
        const float2 aA = *(const float2*)(alphas + eids[rs + base] * 2);
        const bool hasB = (base + 1) < deg;
        float2 aB = float2{0.f, 0.f};
        if (hasB) aB = *(const float2*)(alphas + eids[rs + base + 1] * 2);
        __syncthreads();   // pair tiles ready (pk-1 slots fully read pre-barrier)

        if (base + 2 < deg) {
            const ushort_t* pA = out1 + srcids[rs + base + 2] * (NB * LSEQ * HDIM);
#pragma unroll
            for (int p = 0; p < 2; ++p) pfA[p] = *(const uint2*)(pA + glo[p]);
        }
        if (base + 3 < deg) {
            const ushort_t* pB = out1 + srcids[rs + base + 3] * (NB * LSEQ * HDIM);
#pragma unroll
            for (int p = 0; p < 2; ++p) pfB[p] = *(const uint2*)(pB + glo[p]);
        }

        process(SA, aA);
        if (hasB) process(SB, aB);
    }

    // single non-atomic bf16 store of this third-node's aggregate
#pragma unroll
    for (int mt = 0; mt < 2; ++mt)
#pragma unroll
        for (int g2 = 0; g2 < 4; ++g2) {
            const int gr = mh * 32 + mt * 16 + quad * 4 + g2;  // = l*8 + b
            const int b = gr & 7, l = gr >> 3;
            agg[(i * 96 + b * 12 + l) * 64 + n] = fbf(accN[mt][g2]);
        }
}

// ---------------------------------------------------------------------------
// GRU2 (R18 version, validated): gi AND gh via MFMA; x = relu(agg bf16).
// 16 seqs / 4 waves per block, single barrier per step via H+X ping-pong;
// next x prefetched under MFMAs.
// ---------------------------------------------------------------------------
__global__ __launch_bounds__(256) void gru2_kernel(
    const ushort_t* __restrict__ agg, const float* __restrict__ Wih,
    const float* __restrict__ Whh, const float* __restrict__ bih,
    const float* __restrict__ bhh, float* __restrict__ h2out)
{
    __shared__ ushort_t H[2][16][SST] __attribute__((aligned(16)));
    __shared__ ushort_t X[2][16][SST] __attribute__((aligned(16)));

    const int tid = threadIdx.x;
    const int nw = tid >> 6;
    const int c = tid & 15;
    const int quad = (tid >> 4) & 3;
    const int j = nw * 16 + c;
    const int s0 = blockIdx.x * 16;
    const int sl = tid >> 3, k0 = (tid & 7) * 8;

    if (tid < 128) *(uint4*)&H[0][tid >> 3][(tid & 7) * 8] = uint4{0, 0, 0, 0};

    bf16x8 Bh[3][2], Bi[3][2];
    float bi[3], bh[3];
#pragma unroll
    for (int g = 0; g < 3; ++g) {
        const int row = g * 64 + j;
        bi[g] = bih[row]; bh[g] = bhh[row];
#pragma unroll
        for (int ks = 0; ks < 2; ++ks) {
            const float* wp = Whh + (row << 6) + ks * 32 + quad * 8;
            float4 wa = *(const float4*)wp;
            float4 wb = *(const float4*)(wp + 4);
            ushort_t tmp[8];
            tmp[0] = fbf(wa.x); tmp[1] = fbf(wa.y); tmp[2] = fbf(wa.z); tmp[3] = fbf(wa.w);
            tmp[4] = fbf(wb.x); tmp[5] = fbf(wb.y); tmp[6] = fbf(wb.z); tmp[7] = fbf(wb.w);
            Bh[g][ks] = *(bf16x8*)tmp;
            const float* wp2 = Wih + (row << 6) + ks * 32 + quad * 8;
            float4 va = *(const float4*)wp2;
            float4 vb = *(const float4*)(wp2 + 4);
            tmp[0] = fbf(va.x); tmp[1] = fbf(va.y); tmp[2] = fbf(va.z); tmp[3] = fbf(va.w);
            tmp[4] = fbf(vb.x); tmp[5] = fbf(vb.y); tmp[6] = fbf(vb.z); tmp[7] = fbf(vb.w);
            Bi[g][ks] = *(bf16x8*)tmp;
        }
    }

    float hold[4];
#pragma unroll
    for (int rg = 0; rg < 4; ++rg) hold[rg] = 0.f;

    if (tid < 128) {
        ushort_t xr[8];
        *(uint4*)xr = *(const uint4*)(agg + (s0 + sl) * (LSEQ * HDIM) + k0);
        ushort_t xs[8];
#pragma unroll
        for (int q = 0; q < 8; ++q) xs[q] = (xr[q] & 0x8000u) ? (ushort_t)0 : xr[q];
        *(uint4*)&X[0][sl][k0] = *(uint4*)xs;
    }

    for (int t = 0; t < LSEQ; ++t) {
        __syncthreads();
        const int rb = t & 1, wb = 1 - rb;
        bf16x8 ah0 = *(const bf16x8*)&H[rb][c][quad * 8];
        bf16x8 ah1 = *(const bf16x8*)&H[rb][c][32 + quad * 8];
        bf16x8 ax0 = *(const bf16x8*)&X[rb][c][quad * 8];
        bf16x8 ax1 = *(const bf16x8*)&X[rb][c][32 + quad * 8];

        ushort_t xr[8];
        if (t < LSEQ - 1 && tid < 128)
            *(uint4*)xr = *(const uint4*)(agg + (s0 + sl) * (LSEQ * HDIM) +
                                          (t + 1) * HDIM + k0);

        f32x4 gh[3], gi[3];
#pragma unroll
        for (int g = 0; g < 3; ++g) {
            f32x4 acc = {0.f, 0.f, 0.f, 0.f};
            acc = __builtin_amdgcn_mfma_f32_16x16x32_bf16(ah0, Bh[g][0], acc, 0, 0, 0);
            acc = __builtin_amdgcn_mfma_f32_16x16x32_bf16(ah1, Bh[g][1], acc, 0, 0, 0);
            gh[g] = acc;
            f32x4 acc2 = {0.f, 0.f, 0.f, 0.f};
            acc2 = __builtin_amdgcn_mfma_f32_16x16x32_bf16(ax0, Bi[g][0], acc2, 0, 0, 0);
            acc2 = __builtin_amdgcn_mfma_f32_16x16x32_bf16(ax1, Bi[g][1], acc2, 0, 0, 0);
            gi[g] = acc2;
        }
#pragma unroll
        for (int rg = 0; rg < 4; ++rg) {
            const int sloc = quad * 4 + rg;
            float r = sigm(bi[0] + gi[0][rg] + bh[0] + gh[0][rg]);
            float z = sigm(bi[1] + gi[1][rg] + bh[1] + gh[1][rg]);
            float n = tanh_fast(bi[2] + gi[2][rg] + r * (bh[2] + gh[2][rg]));
            float hv = (1.f - z) * n + z * hold[rg];
            hold[rg] = hv;
            H[wb][sloc][j] = fbf(hv);
        }
        if (t < LSEQ - 1 && tid < 128) {
            ushort_t xs[8];
#pragma unroll
            for (int q = 0; q < 8; ++q) xs[q] = (xr[q] & 0x8000u) ? (ushort_t)0 : xr[q];
            *(uint4*)&X[wb][sl][k0] = *(uint4*)xs;
        }
    }
#pragma unroll
    for (int rg = 0; rg < 4; ++rg) {
        const int sloc = quad * 4 + rg;
        h2out[(s0 + sloc) * HDIM + j] = hold[rg];
    }
}

extern "C" void kernel_launch(void* const* d_in, const int* in_sizes, int n_in,
                              void* d_out, int out_size, void* d_ws, size_t ws_size,
                              hipStream_t stream)
{
    const float* data     = (const float*)d_in[0];
    const float* features = (const float*)d_in[1];
    const int*   edges    = (const int*)d_in[2];
    const float* Wih1     = (const float*)d_in[3];
    const float* Whh1     = (const float*)d_in[4];
    const float* bih1     = (const float*)d_in[5];
    const float* bhh1     = (const float*)d_in[6];
    const float* W1       = (const float*)d_in[7];
    const float* b1       = (const float*)d_in[8];
    const float* W2       = (const float*)d_in[9];
    const float* b2       = (const float*)d_in[10];
    const float* W3       = (const float*)d_in[11];
    const float* b3       = (const float*)d_in[12];
    const float* Wih2     = (const float*)d_in[13];
    const float* Whh2     = (const float*)d_in[14];
    const float* bih2     = (const float*)d_in[15];
    const float* bhh2     = (const float*)d_in[16];

    float*    out  = (float*)d_out;
    char*     ws   = (char*)d_ws;
    ushort_t* out1 = (ushort_t*)ws;                    // bf16 intermediate
    ushort_t* agg  = (ushort_t*)(ws + OUT1_BYTES);     // bf16 GAT output
    int*      meta = (int*)(ws + OUT1_BYTES + AGG_BYTES);
    int*   degree   = meta;                                 // [2000]
    int*   rowstart = meta + NNODE;                         // [2000]
    int*   srcids   = meta + 2 * NNODE;                     // [16000]
    int*   eids     = meta + 2 * NNODE + NEDGE;             // [16000]
    int*   order    = meta + 2 * NNODE + 2 * NEDGE;         // [2000]
    float* alphas   = (float*)(meta + 3 * NNODE + 2 * NEDGE);  // [36000]

    // 3 dispatches: mega (gru1 || csr+sort || alpha), gat, gru2.
    mega_kernel<<<1001 + 4500, 256, 0, stream>>>(
        data, Wih1, Whh1, bih1, bhh1, out1, out,
        edges, degree, rowstart, srcids, eids, order,
        features, W1, b1, W2, b2, alphas);
    gat_csr_kernel<<<dim3(NNODE, 3), 256, 0, stream>>>(out1, degree, rowstart, srcids,
                                                       eids, order, alphas, W3, b3, agg);
    gru2_kernel<<<NSEQ / 16, 256, 0, stream>>>(agg, Wih2, Whh2, bih2, bhh2,
                                               out + NNODE * NB * HDIM);
}